// Round 12
// baseline (233.913 us; speedup 1.0000x reference)
//
#include <hip/hip_runtime.h>
#include <hip/hip_bf16.h>

// Autoregressive LSTM decoder via bf16 MFMA, torch gate order (i,f,g,o).
// B=262144, P=16, H=32, S=25.  One wave = 32 batch rows.
//
// Round-12 change (single variable vs round 6): OCCUPANCY.
//  * Steady A-fragments (identical across waves) move from 60 VGPRs to LDS
//    (15.4 KB/block), read per-use with ds_read_b128 (conflict-free).
//  * EW packs bf16 pairs immediately (no 16-float transient).
//  * __launch_bounds__(256,4) caps unified regs at 128 -> 4 waves/SIMD
//    (was 2).  Bet: the 225us plateau is residency-bound latency exposure.
//  * Carried: per-step NT stores, k-permutation lane-local B-pack, exp2
//    scales folded into A, shared-denominator sigmoid*tanh.

constexpr int P = 16;
constexpr int H = 32;
constexpr int S = 25;

typedef short        bf16x8 __attribute__((ext_vector_type(8)));
typedef float        f32x16 __attribute__((ext_vector_type(16)));
typedef float        f32x4  __attribute__((ext_vector_type(4)));
typedef unsigned int u32x4  __attribute__((ext_vector_type(4)));

union FragU { u32x4 u; bf16x8 b; };

#if __has_builtin(__builtin_amdgcn_exp2f)
#define EX2 __builtin_amdgcn_exp2f
#else
#define EX2 exp2f
#endif

__device__ __forceinline__ unsigned int pkbf(float lo, float hi) {
    unsigned short a = __builtin_bit_cast(unsigned short, __float2bfloat16(lo));
    unsigned short b = __builtin_bit_cast(unsigned short, __float2bfloat16(hi));
    return (unsigned int)a | ((unsigned int)b << 16);
}

// gate-row exp2 scale: rows [0,32)=i, [32,64)=f, [64,96)=g, [96,128)=o
__device__ __forceinline__ float gate_scale(int r) {
    return (r >= 64 && r < 96) ? -2.8853900817779268f   // g rows: -2*log2(e)
                               : -1.4426950408889634f;  // i,f,o rows: -log2(e)
}

// ---------------- setup: build bf16 A-fragments into ws -------------------
// steady W_aug[160][48]: r<128: Wcomb=Whh+Wih*Wout (k<32), bias at k=32, 0 pad;
//                        128<=r<144: Wout rows, bout at k=32; r>=144: 0.
//                        gate rows (r<128) scaled by gate_scale(r).
// step0  W0_aug[128][64]: k<16: Wih; 16<=k<48: Whh; k=48: b_ih+b_hh; 0 pad.
// fragment slot: logical k = 16c + 8*(v>>1) + 4*hi + 2*(v&1) + b
// word index: steady ((t*3+c)*64 + lane)*4 + v   (t<5,c<3)
//             step0  3840 + ((t*4+c)*64 + lane)*4 + v  (t<4,c<4)
__global__ void setup_frags(const float* __restrict__ Wih, const float* __restrict__ Whh,
                            const float* __restrict__ bih, const float* __restrict__ bhh,
                            const float* __restrict__ Wout, const float* __restrict__ bout,
                            unsigned int* __restrict__ ws)
{
    auto waug = [&](int r, int k) -> float {
        float s = (r < 128) ? gate_scale(r) : 1.0f;
        if (r < 128) {
            if (k < 32) {
                float a = Whh[r * H + k];
                for (int p = 0; p < P; ++p) a += Wih[r * P + p] * Wout[p * H + k];
                return s * a;
            }
            if (k == 32) {
                float a = bih[r] + bhh[r];
                for (int p = 0; p < P; ++p) a += Wih[r * P + p] * bout[p];
                return s * a;
            }
            return 0.0f;
        } else if (r < 144) {
            int p = r - 128;
            if (k < 32)  return Wout[p * H + k];
            if (k == 32) return bout[p];
            return 0.0f;
        }
        return 0.0f;
    };
    auto w0aug = [&](int r, int k) -> float {
        float s = gate_scale(r);
        if (k < 16)  return s * Wih[r * P + k];
        if (k < 48)  return s * Whh[r * H + (k - 16)];
        if (k == 48) return s * (bih[r] + bhh[r]);
        return 0.0f;
    };

    const int tid = threadIdx.x;
    for (int idx = tid; idx < 5 * 3 * 64 * 4; idx += 256) {
        int v = idx & 3, l = (idx >> 2) & 63, tc = idx >> 8;
        int t = tc / 3, c = tc % 3;
        int r = 32 * t + (l & 31);
        int k = 16 * c + 8 * (v >> 1) + 4 * (l >> 5) + 2 * (v & 1);
        ws[idx] = pkbf(waug(r, k), waug(r, k + 1));
    }
    for (int idx = tid; idx < 4 * 4 * 64 * 4; idx += 256) {
        int v = idx & 3, l = (idx >> 2) & 63, tc = idx >> 8;
        int t = tc / 4, c = tc % 4;
        int r = 32 * t + (l & 31);
        int k = 16 * c + 8 * (v >> 1) + 4 * (l >> 5) + 2 * (v & 1);
        ws[3840 + idx] = pkbf(w0aug(r, k), w0aug(r, k + 1));
    }
}

// ------------------------------- main -------------------------------------
__global__ __launch_bounds__(256, 4) void decoder_mfma(
    const float* __restrict__ x0, const float* __restrict__ h0,
    const float* __restrict__ c0, const unsigned int* __restrict__ ws,
    float* __restrict__ out, int batch)
{
    __shared__ unsigned int Alds[5 * 3 * 64 * 4];   // 15.4 KB steady A-frags

    const int lane = threadIdx.x & 63;
    const int wid  = threadIdx.x >> 6;
    const int bcol = lane & 31;
    const int hi   = lane >> 5;
    const int bg   = (blockIdx.x * 4 + wid) * 32 + bcol;  // this lane's batch row

    // stage steady A-fragments to LDS (shared by all 4 waves)
    for (int i = threadIdx.x; i < 5 * 3 * 64 * 4; i += 256) Alds[i] = ws[i];
    __syncthreads();
    if (bg >= batch) return;  // batch % 128 == 0: never taken, kept for safety

    const unsigned int* const Abase = Alds + lane * 4;
    auto ldA = [&](int t, int c) -> FragU {   // t,c compile-time after unroll
        FragU a;
        a.u = *reinterpret_cast<const u32x4*>(Abase + (t * 3 + c) * 256);
        return a;
    };

    // bias B-chunk: logical k=32 (steady) / k=48 (step0) at (hi=0, v=0, lo half)
    FragU Bbias;
    Bbias.u.x = (hi == 0) ? 0x3F80u : 0u;  // bf16(1.0)
    Bbias.u.y = 0u; Bbias.u.z = 0u; Bbias.u.w = 0u;

    // cell state in D-layout: cc[r] <-> c[bg][(r&3) + 8*(r>>2) + 4*hi]
    float cc[16];
    #pragma unroll
    for (int q = 0; q < 4; ++q) {
        f32x4 t = *reinterpret_cast<const f32x4*>(c0 + (size_t)bg * H + q * 8 + 4 * hi);
        cc[q * 4 + 0] = t.x; cc[q * 4 + 1] = t.y; cc[q * 4 + 2] = t.z; cc[q * 4 + 3] = t.w;
    }

    const f32x16 vzero = {};
    f32x16 acc[4];
    FragU Bh[2];

    // ---- step-0 gates: K = [x0(16) | h0(32) | 1], W0_aug fragments ----
    {
        FragU B0[4];
        {
            const float* p = x0 + (size_t)bg * P;
            f32x4 a  = *reinterpret_cast<const f32x4*>(p + 4 * hi);
            f32x4 b4 = *reinterpret_cast<const f32x4*>(p + 8 + 4 * hi);
            B0[0].u.x = pkbf(a.x, a.y);  B0[0].u.y = pkbf(a.z, a.w);
            B0[0].u.z = pkbf(b4.x, b4.y); B0[0].u.w = pkbf(b4.z, b4.w);
        }
        #pragma unroll
        for (int ch = 0; ch < 2; ++ch) {
            const float* p = h0 + (size_t)bg * H + 16 * ch;
            f32x4 a  = *reinterpret_cast<const f32x4*>(p + 4 * hi);
            f32x4 b4 = *reinterpret_cast<const f32x4*>(p + 8 + 4 * hi);
            B0[1 + ch].u.x = pkbf(a.x, a.y);  B0[1 + ch].u.y = pkbf(a.z, a.w);
            B0[1 + ch].u.z = pkbf(b4.x, b4.y); B0[1 + ch].u.w = pkbf(b4.z, b4.w);
        }
        B0[3] = Bbias;

        #pragma unroll
        for (int t = 0; t < 4; ++t) acc[t] = vzero;
        #pragma unroll
        for (int c4 = 0; c4 < 4; ++c4) {
            #pragma unroll
            for (int t = 0; t < 4; ++t) {
                FragU a;
                a.u = *reinterpret_cast<const u32x4*>(ws + 3840 + ((t * 4 + c4) * 64 + lane) * 4);
                acc[t] = __builtin_amdgcn_mfma_f32_32x32x16_bf16(a.b, B0[c4].b, acc[t], 0, 0, 0);
            }
        }
    }

    // ---------------- per-step phases (compile-time indexed) --------------
    auto EWPACK = [&]() {
        #pragma unroll
        for (int i = 0; i < 8; ++i) {
            float h2[2];
            #pragma unroll
            for (int j = 0; j < 2; ++j) {
                const int r = 2 * i + j;
                const float ei = EX2(acc[0][r]);        // e^{-i}
                const float ef = EX2(acc[1][r]);        // e^{-f}
                const float eg = EX2(acc[2][r]);        // e^{-2g}
                const float eo = EX2(acc[3][r]);        // e^{-o}
                const float r1 = __builtin_amdgcn_rcpf((1.0f + ei) * (1.0f + eg));
                const float tg = (1.0f - eg) * r1;      // sig(i)*tanh(g)
                const float rf = __builtin_amdgcn_rcpf(1.0f + ef);
                const float cn = __builtin_fmaf(cc[r], rf, tg);
                cc[r] = cn;
                const float ec = EX2(cn * -2.8853900817779268f);  // e^{-2cn}
                const float r2 = __builtin_amdgcn_rcpf((1.0f + ec) * (1.0f + eo));
                h2[j] = (1.0f - ec) * r2;               // sig(o)*tanh(cn)
            }
            Bh[i >> 2].u[i & 3] = pkbf(h2[0], h2[1]);   // static after unroll
        }
    };
    auto PROJSTORE = [&](int s) {
        FragU a;
        f32x16 px;
        a = ldA(4, 2); px = __builtin_amdgcn_mfma_f32_32x32x16_bf16(a.b, Bbias.b, vzero, 0, 0, 0);
        a = ldA(4, 0); px = __builtin_amdgcn_mfma_f32_32x32x16_bf16(a.b, Bh[0].b, px,    0, 0, 0);
        a = ldA(4, 1); px = __builtin_amdgcn_mfma_f32_32x32x16_bf16(a.b, Bh[1].b, px,    0, 0, 0);
        float* op = out + ((size_t)bg * S + s) * P + 4 * hi;
        f32x4 v0 = {px[0], px[1], px[2], px[3]};
        f32x4 v1 = {px[4], px[5], px[6], px[7]};
        __builtin_nontemporal_store(v0, reinterpret_cast<f32x4*>(op));
        __builtin_nontemporal_store(v1, reinterpret_cast<f32x4*>(op + 8));
    };
    auto GATES = [&]() {
        #pragma unroll
        for (int t = 0; t < 4; ++t) {
            FragU a;
            f32x16 g;
            a = ldA(t, 2); g = __builtin_amdgcn_mfma_f32_32x32x16_bf16(a.b, Bbias.b, vzero, 0, 0, 0);
            a = ldA(t, 0); g = __builtin_amdgcn_mfma_f32_32x32x16_bf16(a.b, Bh[0].b, g,    0, 0, 0);
            a = ldA(t, 1); g = __builtin_amdgcn_mfma_f32_32x32x16_bf16(a.b, Bh[1].b, g,    0, 0, 0);
            acc[t] = g;
        }
    };

    // ---- steady loop ----
    for (int s = 0; s < S; ++s) {
        EWPACK();
        PROJSTORE(s);
        if (s + 1 < S) GATES();
    }
}

extern "C" void kernel_launch(void* const* d_in, const int* in_sizes, int n_in,
                              void* d_out, int out_size, void* d_ws, size_t ws_size,
                              hipStream_t stream) {
    const float* x0   = (const float*)d_in[0];
    const float* h0   = (const float*)d_in[1];
    const float* c0   = (const float*)d_in[2];
    const float* Wih  = (const float*)d_in[3];
    const float* Whh  = (const float*)d_in[4];
    const float* bih  = (const float*)d_in[5];
    const float* bhh  = (const float*)d_in[6];
    const float* Wout = (const float*)d_in[7];
    const float* bout = (const float*)d_in[8];
    float* out = (float*)d_out;
    unsigned int* ws = (unsigned int*)d_ws;

    const int batch = in_sizes[0] / P;  // 262144

    hipLaunchKernelGGL(setup_frags, dim3(1), dim3(256), 0, stream,
                       Wih, Whh, bih, bhh, Wout, bout, ws);

    dim3 block(256);                    // 4 waves x 32 batch rows = 128 batch/block
    dim3 grid((batch + 127) / 128);     // 2048 blocks
    hipLaunchKernelGGL(decoder_mfma, grid, block, 0, stream,
                       x0, h0, c0, ws, out, batch);
}